// Round 1
// baseline (1419.017 us; speedup 1.0000x reference)
//
#include <hip/hip_runtime.h>
#include <math.h>

#define BB 8
#define CCH 256          // channels
#define NN 2304          // H*W = 48*48
#define NH 4
#define HDIM 64
#define QKV_ROWS 384
#define SCALE 0.125f
#define BN_EPS 1e-5f
#define NTILES 36        // NN / 64

// ---------------------------------------------------------------------------
// K1: qkv[b][o][n] = sum_c W[o][c] * x[b][c][n], W = concat(q_w, k_w, v_w)
// grid (36, 6, 8), 256 threads, 64x64 tile, 4x4 per thread
// ---------------------------------------------------------------------------
__global__ __launch_bounds__(256) void qkv_gemm_k(
    const float* __restrict__ x, const float* __restrict__ qw,
    const float* __restrict__ kw, const float* __restrict__ vw,
    float* __restrict__ qkv)
{
    __shared__ float Wl[64][17];
    __shared__ float Xl[16][68];
    const int tid = threadIdx.x;
    const int nb = blockIdx.x * 64;
    const int ob = blockIdx.y * 64;
    const int b  = blockIdx.z;
    const int tn = (tid & 15) * 4;
    const int to = (tid >> 4) * 4;

    const int wrow = tid >> 2;          // 0..63 (o within tile)
    const int wc4  = (tid & 3) * 4;     // 0,4,8,12
    const int o = ob + wrow;
    const float* wsrc;
    if (o < 256)      wsrc = qw + (size_t)o * CCH;
    else if (o < 320) wsrc = kw + (size_t)(o - 256) * CCH;
    else              wsrc = vw + (size_t)(o - 320) * CCH;

    const int xrow = tid >> 4;          // 0..15 (c within tile)
    const int xn4  = (tid & 15) * 4;
    const float* xsrc = x + ((size_t)b * CCH + xrow) * NN + nb + xn4;

    float acc[4][4] = {};

    for (int c0 = 0; c0 < CCH; c0 += 16) {
        float4 wv = *(const float4*)(wsrc + c0 + wc4);
        float4 xv = *(const float4*)(xsrc + (size_t)c0 * NN);
        Wl[wrow][wc4+0] = wv.x; Wl[wrow][wc4+1] = wv.y;
        Wl[wrow][wc4+2] = wv.z; Wl[wrow][wc4+3] = wv.w;
        Xl[xrow][xn4+0] = xv.x; Xl[xrow][xn4+1] = xv.y;
        Xl[xrow][xn4+2] = xv.z; Xl[xrow][xn4+3] = xv.w;
        __syncthreads();
        #pragma unroll
        for (int kk = 0; kk < 16; ++kk) {
            float a0 = Wl[to+0][kk], a1 = Wl[to+1][kk];
            float a2 = Wl[to+2][kk], a3 = Wl[to+3][kk];
            float b0 = Xl[kk][tn+0], b1 = Xl[kk][tn+1];
            float b2 = Xl[kk][tn+2], b3 = Xl[kk][tn+3];
            acc[0][0] += a0*b0; acc[0][1] += a0*b1; acc[0][2] += a0*b2; acc[0][3] += a0*b3;
            acc[1][0] += a1*b0; acc[1][1] += a1*b1; acc[1][2] += a1*b2; acc[1][3] += a1*b3;
            acc[2][0] += a2*b0; acc[2][1] += a2*b1; acc[2][2] += a2*b2; acc[2][3] += a2*b3;
            acc[3][0] += a3*b0; acc[3][1] += a3*b1; acc[3][2] += a3*b2; acc[3][3] += a3*b3;
        }
        __syncthreads();
    }
    float* dst = qkv + ((size_t)b * QKV_ROWS + ob + to) * NN + nb + tn;
    #pragma unroll
    for (int i = 0; i < 4; ++i) {
        float4 v = make_float4(acc[i][0], acc[i][1], acc[i][2], acc[i][3]);
        *(float4*)(dst + (size_t)i * NN) = v;
    }
}

// ---------------------------------------------------------------------------
// K2: MQA attention, one block per (b, h, 64-query tile). Max-free softmax
// (scores bounded: |q.k|/8 <~ 15, exp safe in fp32). P overwrites K in LDS.
// Thread owns rows n = tn+16i (i=0..3), cols (m or d) = tm*4+j.
// ---------------------------------------------------------------------------
__global__ __launch_bounds__(256) void attn_k(
    const float* __restrict__ qkv, float* __restrict__ attn_out)
{
    __shared__ float Qt[64][68];   // [n][d]
    __shared__ float KS[64][68];   // K tile [d][m], then P tile [n][m]
    __shared__ float Vt[64][68];   // [m][d]

    const int tid = threadIdx.x;
    const int tn = tid & 15;
    const int tm = tid >> 4;       // 0..15
    const int nb = blockIdx.x * 64;
    const int h  = blockIdx.y;
    const int b  = blockIdx.z;

    const float* qbase = qkv + ((size_t)b * QKV_ROWS + h * HDIM) * NN + nb;
    const float* kbase = qkv + ((size_t)b * QKV_ROWS + 256) * NN;
    const float* vbase = qkv + ((size_t)b * QKV_ROWS + 320) * NN;

    // load Q tile transposed: q[d][nb+n] -> Qt[n][d]
    #pragma unroll
    for (int u = 0; u < 4; ++u) {
        int flat = tid + 256 * u;
        int drow = flat >> 4;          // 0..63
        int n4   = (flat & 15) * 4;    // 0..60
        float4 qv = *(const float4*)(qbase + (size_t)drow * NN + n4);
        Qt[n4+0][drow] = qv.x; Qt[n4+1][drow] = qv.y;
        Qt[n4+2][drow] = qv.z; Qt[n4+3][drow] = qv.w;
    }

    float o_[4][4] = {};
    float lacc[4] = {0.f, 0.f, 0.f, 0.f};
    __syncthreads();

    for (int t = 0; t < NTILES; ++t) {
        const int m0g = t * 64;
        // load K tile [d][m] and V tile transposed [m][d]
        #pragma unroll
        for (int u = 0; u < 4; ++u) {
            int flat = tid + 256 * u;
            int row = flat >> 4;           // d
            int m4  = (flat & 15) * 4;     // m
            float4 kv = *(const float4*)(kbase + (size_t)row * NN + m0g + m4);
            float4 vv = *(const float4*)(vbase + (size_t)row * NN + m0g + m4);
            *(float4*)&KS[row][m4] = kv;
            Vt[m4+0][row] = vv.x; Vt[m4+1][row] = vv.y;
            Vt[m4+2][row] = vv.z; Vt[m4+3][row] = vv.w;
        }
        __syncthreads();

        // S = Qt . K
        float s[4][4] = {};
        for (int d0 = 0; d0 < 64; d0 += 4) {
            float4 qv[4], kv[4];
            #pragma unroll
            for (int i = 0; i < 4; ++i) qv[i] = *(const float4*)&Qt[tn + 16*i][d0];
            #pragma unroll
            for (int k = 0; k < 4; ++k) kv[k] = *(const float4*)&KS[d0 + k][tm*4];
            #pragma unroll
            for (int i = 0; i < 4; ++i) {
                float a0 = qv[i].x, a1 = qv[i].y, a2 = qv[i].z, a3 = qv[i].w;
                s[i][0] += a0*kv[0].x + a1*kv[1].x + a2*kv[2].x + a3*kv[3].x;
                s[i][1] += a0*kv[0].y + a1*kv[1].y + a2*kv[2].y + a3*kv[3].y;
                s[i][2] += a0*kv[0].z + a1*kv[1].z + a2*kv[2].z + a3*kv[3].z;
                s[i][3] += a0*kv[0].w + a1*kv[1].w + a2*kv[2].w + a3*kv[3].w;
            }
        }
        // exponentiate (max-free), accumulate row-sum partials
        #pragma unroll
        for (int i = 0; i < 4; ++i) {
            #pragma unroll
            for (int j = 0; j < 4; ++j) {
                float p = __expf(s[i][j] * SCALE);
                s[i][j] = p;
                lacc[i] += p;
            }
        }
        __syncthreads();   // all K reads done before overwriting KS with P
        #pragma unroll
        for (int i = 0; i < 4; ++i)
            *(float4*)&KS[tn + 16*i][tm*4] = make_float4(s[i][0], s[i][1], s[i][2], s[i][3]);
        __syncthreads();

        // O += P . Vt
        for (int m0 = 0; m0 < 64; m0 += 4) {
            float4 pv[4], vv[4];
            #pragma unroll
            for (int i = 0; i < 4; ++i) pv[i] = *(const float4*)&KS[tn + 16*i][m0];
            #pragma unroll
            for (int k = 0; k < 4; ++k) vv[k] = *(const float4*)&Vt[m0 + k][tm*4];
            #pragma unroll
            for (int i = 0; i < 4; ++i) {
                float a0 = pv[i].x, a1 = pv[i].y, a2 = pv[i].z, a3 = pv[i].w;
                o_[i][0] += a0*vv[0].x + a1*vv[1].x + a2*vv[2].x + a3*vv[3].x;
                o_[i][1] += a0*vv[0].y + a1*vv[1].y + a2*vv[2].y + a3*vv[3].y;
                o_[i][2] += a0*vv[0].z + a1*vv[1].z + a2*vv[2].z + a3*vv[3].z;
                o_[i][3] += a0*vv[0].w + a1*vv[1].w + a2*vv[2].w + a3*vv[3].w;
            }
        }
        __syncthreads();   // protect KS/Vt before next tile's loads
    }

    // reduce softmax denominators across the 16 tm groups (reuse KS as scratch)
    float (*red)[17] = reinterpret_cast<float(*)[17]>(&KS[0][0]);
    #pragma unroll
    for (int i = 0; i < 4; ++i) red[tn + 16*i][tm] = lacc[i];
    __syncthreads();

    float* obase = attn_out + ((size_t)b * CCH + h * HDIM) * NN + nb;
    #pragma unroll
    for (int i = 0; i < 4; ++i) {
        float lsum = 0.f;
        #pragma unroll
        for (int t2 = 0; t2 < 16; ++t2) lsum += red[tn + 16*i][t2];
        float rinv = 1.0f / lsum;
        #pragma unroll
        for (int j = 0; j < 4; ++j)
            obase[(size_t)(tm*4 + j) * NN + tn + 16*i] = o_[i][j] * rinv;
    }
}

// ---------------------------------------------------------------------------
// K3: proj[b][c][n] = sum_o pw[c][o] * attn[b][o][n] + pb[c]
// ---------------------------------------------------------------------------
__global__ __launch_bounds__(256) void proj_gemm_k(
    const float* __restrict__ ain, const float* __restrict__ pw,
    const float* __restrict__ pb, float* __restrict__ pout)
{
    __shared__ float Wl[64][17];
    __shared__ float Xl[16][68];
    const int tid = threadIdx.x;
    const int nb = blockIdx.x * 64;
    const int ob = blockIdx.y * 64;
    const int b  = blockIdx.z;
    const int tn = (tid & 15) * 4;
    const int to = (tid >> 4) * 4;

    const int wrow = tid >> 2;
    const int wc4  = (tid & 3) * 4;
    const float* wsrc = pw + (size_t)(ob + wrow) * CCH;

    const int xrow = tid >> 4;
    const int xn4  = (tid & 15) * 4;
    const float* xsrc = ain + ((size_t)b * CCH + xrow) * NN + nb + xn4;

    float acc[4][4] = {};

    for (int c0 = 0; c0 < CCH; c0 += 16) {
        float4 wv = *(const float4*)(wsrc + c0 + wc4);
        float4 xv = *(const float4*)(xsrc + (size_t)c0 * NN);
        Wl[wrow][wc4+0] = wv.x; Wl[wrow][wc4+1] = wv.y;
        Wl[wrow][wc4+2] = wv.z; Wl[wrow][wc4+3] = wv.w;
        Xl[xrow][xn4+0] = xv.x; Xl[xrow][xn4+1] = xv.y;
        Xl[xrow][xn4+2] = xv.z; Xl[xrow][xn4+3] = xv.w;
        __syncthreads();
        #pragma unroll
        for (int kk = 0; kk < 16; ++kk) {
            float a0 = Wl[to+0][kk], a1 = Wl[to+1][kk];
            float a2 = Wl[to+2][kk], a3 = Wl[to+3][kk];
            float b0 = Xl[kk][tn+0], b1 = Xl[kk][tn+1];
            float b2 = Xl[kk][tn+2], b3 = Xl[kk][tn+3];
            acc[0][0] += a0*b0; acc[0][1] += a0*b1; acc[0][2] += a0*b2; acc[0][3] += a0*b3;
            acc[1][0] += a1*b0; acc[1][1] += a1*b1; acc[1][2] += a1*b2; acc[1][3] += a1*b3;
            acc[2][0] += a2*b0; acc[2][1] += a2*b1; acc[2][2] += a2*b2; acc[2][3] += a2*b3;
            acc[3][0] += a3*b0; acc[3][1] += a3*b1; acc[3][2] += a3*b2; acc[3][3] += a3*b3;
        }
        __syncthreads();
    }
    float* dst = pout + ((size_t)b * CCH + ob + to) * NN + nb + tn;
    #pragma unroll
    for (int i = 0; i < 4; ++i) {
        float bias = pb[ob + to + i];
        float4 v = make_float4(acc[i][0] + bias, acc[i][1] + bias,
                               acc[i][2] + bias, acc[i][3] + bias);
        *(float4*)(dst + (size_t)i * NN) = v;
    }
}

// ---------------------------------------------------------------------------
// K4: per-channel batch stats -> scale/shift.  grid = 256 blocks (1/channel)
// ---------------------------------------------------------------------------
__global__ __launch_bounds__(256) void bn_stats_k(
    const float* __restrict__ proj, const float* __restrict__ gamma,
    const float* __restrict__ beta, float* __restrict__ stats)
{
    const int c = blockIdx.x;
    const int tid = threadIdx.x;
    float s = 0.f, s2 = 0.f;
    for (int b = 0; b < BB; ++b) {
        const float* p = proj + ((size_t)b * CCH + c) * NN;
        for (int n = tid * 4; n < NN; n += 1024) {
            float4 v = *(const float4*)(p + n);
            s  += v.x + v.y + v.z + v.w;
            s2 += v.x*v.x + v.y*v.y + v.z*v.z + v.w*v.w;
        }
    }
    __shared__ float rs[256], rs2[256];
    rs[tid] = s; rs2[tid] = s2;
    __syncthreads();
    for (int off = 128; off > 0; off >>= 1) {
        if (tid < off) { rs[tid] += rs[tid + off]; rs2[tid] += rs2[tid + off]; }
        __syncthreads();
    }
    if (tid == 0) {
        const float inv_n = 1.0f / (float)(BB * NN);
        float mean = rs[0] * inv_n;
        float var  = rs2[0] * inv_n - mean * mean;
        float sc = gamma[c] * rsqrtf(var + BN_EPS);
        stats[c] = sc;
        stats[CCH + c] = beta[c] - mean * sc;
    }
}

// ---------------------------------------------------------------------------
// K5: out = scale[c]*proj + shift[c] + x
// ---------------------------------------------------------------------------
__global__ __launch_bounds__(256) void bn_apply_k(
    const float* __restrict__ proj, const float* __restrict__ x,
    const float* __restrict__ stats, float* __restrict__ out)
{
    size_t idx = ((size_t)blockIdx.x * 256 + threadIdx.x) * 4;
    const size_t total = (size_t)BB * CCH * NN;
    if (idx >= total) return;
    int c = (int)((idx / NN) % CCH);
    float sc = stats[c], sh = stats[CCH + c];
    float4 p  = *(const float4*)(proj + idx);
    float4 xv = *(const float4*)(x + idx);
    float4 r;
    r.x = sc * p.x + sh + xv.x;
    r.y = sc * p.y + sh + xv.y;
    r.z = sc * p.z + sh + xv.z;
    r.w = sc * p.w + sh + xv.w;
    *(float4*)(out + idx) = r;
}

extern "C" void kernel_launch(void* const* d_in, const int* in_sizes, int n_in,
                              void* d_out, int out_size, void* d_ws, size_t ws_size,
                              hipStream_t stream)
{
    const float* x     = (const float*)d_in[0];
    const float* qw    = (const float*)d_in[1];
    const float* kw    = (const float*)d_in[2];
    const float* vw    = (const float*)d_in[3];
    const float* pw    = (const float*)d_in[4];
    const float* pb    = (const float*)d_in[5];
    const float* gamma = (const float*)d_in[6];
    const float* beta  = (const float*)d_in[7];
    float* out = (float*)d_out;

    float* qkv   = (float*)d_ws;                              // 8*384*2304 floats
    float* attn  = qkv + (size_t)BB * QKV_ROWS * NN;          // 8*256*2304 floats
    float* proj  = (float*)d_ws;                              // reuse qkv region
    float* stats = attn + (size_t)BB * CCH * NN;              // 512 floats

    dim3 g1(NN / 64, QKV_ROWS / 64, BB);
    qkv_gemm_k<<<g1, 256, 0, stream>>>(x, qw, kw, vw, qkv);

    dim3 g2(NN / 64, NH, BB);
    attn_k<<<g2, 256, 0, stream>>>(qkv, attn);

    dim3 g3(NN / 64, CCH / 64, BB);
    proj_gemm_k<<<g3, 256, 0, stream>>>(attn, pw, pb, proj);

    bn_stats_k<<<CCH, 256, 0, stream>>>(proj, gamma, beta, stats);

    int total4 = BB * CCH * NN / 4;
    bn_apply_k<<<(total4 + 255) / 256, 256, 0, stream>>>(proj, x, stats, out);
}

// Round 2
// 288.397 us; speedup vs baseline: 4.9204x; 4.9204x over previous
//
#include <hip/hip_runtime.h>
#include <math.h>

#define BB 8
#define CCH 256          // channels
#define NN 2304          // H*W = 48*48
#define NH 4
#define HDIM 64
#define QKV_ROWS 384
#define SCALE 0.125f
#define BN_EPS 1e-5f
#define NTILES 36        // NN / 64
#define LW 72            // padded bf16 row pitch for 64-wide LDS tiles

typedef short bf16x8 __attribute__((ext_vector_type(8)));
typedef float f32x4 __attribute__((ext_vector_type(4)));
typedef unsigned short us4 __attribute__((ext_vector_type(4)));

__device__ __forceinline__ unsigned short f2bf(float f) {
    unsigned u = __float_as_uint(f);
    u = (u + 0x7FFFu + ((u >> 16) & 1u)) >> 16;
    return (unsigned short)u;
}

// ---------------------------------------------------------------------------
// K1: qkv GEMM -> bf16 outputs in attention-ready layouts:
//   Qt[b][n][256]  (o = h*64+d)     for blockIdx.y 0..3
//   Kt[b][n][64]                    for blockIdx.y == 4
//   Vn[b][d][n]                     for blockIdx.y == 5
// grid (36, 6, 8), 256 threads, 64x64 tile, 4x4 per thread (fp32 VALU)
// ---------------------------------------------------------------------------
__global__ __launch_bounds__(256) void qkv_gemm_k(
    const float* __restrict__ x, const float* __restrict__ qw,
    const float* __restrict__ kw, const float* __restrict__ vw,
    unsigned short* __restrict__ Qt, unsigned short* __restrict__ Kt,
    unsigned short* __restrict__ Vn)
{
    __shared__ float Wl[64][17];
    __shared__ float Xl[16][68];
    const int tid = threadIdx.x;
    const int nb = blockIdx.x * 64;
    const int ob = blockIdx.y * 64;
    const int b  = blockIdx.z;
    const int tn = (tid & 15) * 4;
    const int to = (tid >> 4) * 4;

    const int wrow = tid >> 2;          // 0..63 (o within tile)
    const int wc4  = (tid & 3) * 4;     // 0,4,8,12
    const int o = ob + wrow;
    const float* wsrc;
    if (o < 256)      wsrc = qw + (size_t)o * CCH;
    else if (o < 320) wsrc = kw + (size_t)(o - 256) * CCH;
    else              wsrc = vw + (size_t)(o - 320) * CCH;

    const int xrow = tid >> 4;          // 0..15 (c within tile)
    const int xn4  = (tid & 15) * 4;
    const float* xsrc = x + ((size_t)b * CCH + xrow) * NN + nb + xn4;

    float acc[4][4] = {};

    for (int c0 = 0; c0 < CCH; c0 += 16) {
        float4 wv = *(const float4*)(wsrc + c0 + wc4);
        float4 xv = *(const float4*)(xsrc + (size_t)c0 * NN);
        Wl[wrow][wc4+0] = wv.x; Wl[wrow][wc4+1] = wv.y;
        Wl[wrow][wc4+2] = wv.z; Wl[wrow][wc4+3] = wv.w;
        Xl[xrow][xn4+0] = xv.x; Xl[xrow][xn4+1] = xv.y;
        Xl[xrow][xn4+2] = xv.z; Xl[xrow][xn4+3] = xv.w;
        __syncthreads();
        #pragma unroll
        for (int kk = 0; kk < 16; ++kk) {
            float a0 = Wl[to+0][kk], a1 = Wl[to+1][kk];
            float a2 = Wl[to+2][kk], a3 = Wl[to+3][kk];
            float b0 = Xl[kk][tn+0], b1 = Xl[kk][tn+1];
            float b2 = Xl[kk][tn+2], b3 = Xl[kk][tn+3];
            acc[0][0] += a0*b0; acc[0][1] += a0*b1; acc[0][2] += a0*b2; acc[0][3] += a0*b3;
            acc[1][0] += a1*b0; acc[1][1] += a1*b1; acc[1][2] += a1*b2; acc[1][3] += a1*b3;
            acc[2][0] += a2*b0; acc[2][1] += a2*b1; acc[2][2] += a2*b2; acc[2][3] += a2*b3;
            acc[3][0] += a3*b0; acc[3][1] += a3*b1; acc[3][2] += a3*b2; acc[3][3] += a3*b3;
        }
        __syncthreads();
    }

    if (ob < 256) {
        // Qt[b][n][o']: consecutive o' = acc[0..3][j]
        #pragma unroll
        for (int j = 0; j < 4; ++j) {
            us4 v = { f2bf(acc[0][j]), f2bf(acc[1][j]), f2bf(acc[2][j]), f2bf(acc[3][j]) };
            *(us4*)(Qt + ((size_t)(b * NN + nb + tn + j)) * 256 + ob + to) = v;
        }
    } else if (ob < 320) {
        // Kt[b][n][d]
        #pragma unroll
        for (int j = 0; j < 4; ++j) {
            us4 v = { f2bf(acc[0][j]), f2bf(acc[1][j]), f2bf(acc[2][j]), f2bf(acc[3][j]) };
            *(us4*)(Kt + ((size_t)(b * NN + nb + tn + j)) * 64 + (ob - 256) + to) = v;
        }
    } else {
        // Vn[b][d][n]: consecutive n = acc[i][0..3]
        #pragma unroll
        for (int i = 0; i < 4; ++i) {
            us4 v = { f2bf(acc[i][0]), f2bf(acc[i][1]), f2bf(acc[i][2]), f2bf(acc[i][3]) };
            *(us4*)(Vn + ((size_t)(b * 64 + (ob - 320) + to + i)) * NN + nb + tn) = v;
        }
    }
}

// ---------------------------------------------------------------------------
// K2: MFMA attention. grid (36 qtiles, 2 head-pairs, 8 b), 256 threads.
// Wave w: head = by*2 + (w>>1), queries qoff = (w&1)*32 within the 64-q tile.
// Max-free softmax; P round-trips LDS (C-layout -> A-layout); O transposed
// through LDS for coalesced fp32 stores.
// ---------------------------------------------------------------------------
__global__ __launch_bounds__(256, 3) void attn_k(
    const unsigned short* __restrict__ Qt,  // [B][N][256] bf16
    const unsigned short* __restrict__ Kt,  // [B][N][64]  bf16
    const unsigned short* __restrict__ Vn,  // [B][64][N]  bf16
    float* __restrict__ attn_out)           // [B][256][N] fp32
{
    __shared__ __align__(16) char smem[36864];
    unsigned short* sK = (unsigned short*)smem;            // [64][LW]
    unsigned short* sV = (unsigned short*)(smem + 9216);   // [64][LW]
    unsigned short* sP = (unsigned short*)(smem + 18432);  // [2][64][LW]
    float* sT = (float*)smem;                              // [2][64][68] (reused)

    const int tid  = threadIdx.x;
    const int wave = tid >> 6;
    const int lane = tid & 63;
    const int quad = lane >> 4;
    const int l15  = lane & 15;
    const int hloc = wave >> 1;          // 0/1 within head pair
    const int qoff = (wave & 1) * 32;    // query offset within 64-tile
    const int nb   = blockIdx.x * 64;
    const int head = blockIdx.y * 2 + hloc;
    const int b    = blockIdx.z;

    unsigned short* sPh = sP + hloc * 64 * LW;

    // Q A-fragments (held in registers whole kernel): A[m=l15][k=quad*8+j]
    bf16x8 aQ[2][2];
    #pragma unroll
    for (int i = 0; i < 2; ++i)
        #pragma unroll
        for (int s = 0; s < 2; ++s) {
            const unsigned short* p = Qt +
                ((size_t)(b * NN + nb + qoff + 16 * i + l15)) * 256 +
                head * 64 + s * 32 + quad * 8;
            aQ[i][s] = *(const bf16x8*)p;
        }

    f32x4 O[2][4] = {};
    float lacc[2][4] = {};

    // tile-0 prefetch into registers
    bf16x8 pK[2], pV[2];
    {
        #pragma unroll
        for (int u = 0; u < 2; ++u) {
            int flat = tid + 256 * u;
            int row = flat >> 3;
            int ch  = (flat & 7) * 8;
            pK[u] = *(const bf16x8*)(Kt + ((size_t)(b * NN + row)) * 64 + ch);
            pV[u] = *(const bf16x8*)(Vn + ((size_t)(b * 64 + row)) * NN + ch);
        }
    }

    for (int t = 0; t < NTILES; ++t) {
        __syncthreads();   // previous tile's LDS reads complete
        #pragma unroll
        for (int u = 0; u < 2; ++u) {
            int flat = tid + 256 * u;
            int row = flat >> 3;
            int ch  = (flat & 7) * 8;
            *(bf16x8*)(sK + row * LW + ch) = pK[u];
            *(bf16x8*)(sV + row * LW + ch) = pV[u];
        }
        __syncthreads();

        if (t + 1 < NTILES) {
            int m0n = (t + 1) * 64;
            #pragma unroll
            for (int u = 0; u < 2; ++u) {
                int flat = tid + 256 * u;
                int row = flat >> 3;
                int ch  = (flat & 7) * 8;
                pK[u] = *(const bf16x8*)(Kt + ((size_t)(b * NN + m0n + row)) * 64 + ch);
                pV[u] = *(const bf16x8*)(Vn + ((size_t)(b * 64 + row)) * NN + m0n + ch);
            }
        }

        // S = Q . K^T : C[i][j], i = 16-query tile, j = 16-key tile
        f32x4 C[2][4] = {};
        #pragma unroll
        for (int s = 0; s < 2; ++s) {
            #pragma unroll
            for (int j = 0; j < 4; ++j) {
                bf16x8 bK = *(const bf16x8*)(sK + (16 * j + l15) * LW + s * 32 + quad * 8);
                C[0][j] = __builtin_amdgcn_mfma_f32_16x16x32_bf16(aQ[0][s], bK, C[0][j], 0, 0, 0);
                C[1][j] = __builtin_amdgcn_mfma_f32_16x16x32_bf16(aQ[1][s], bK, C[1][j], 0, 0, 0);
            }
        }

        // exp (max-free), accumulate row partials, write P (bf16) to LDS.
        // C layout: col = l15 (key), row = quad*4+r (query)
        #pragma unroll
        for (int i = 0; i < 2; ++i)
            #pragma unroll
            for (int j = 0; j < 4; ++j)
                #pragma unroll
                for (int r = 0; r < 4; ++r) {
                    float p = __expf(C[i][j][r] * SCALE);
                    lacc[i][r] += p;
                    sPh[(qoff + 16 * i + quad * 4 + r) * LW + 16 * j + l15] = f2bf(p);
                }

        // O += P . V^T  (A = P rows of this wave, B from sV[dim][key])
        #pragma unroll
        for (int s = 0; s < 2; ++s) {
            bf16x8 aP0 = *(const bf16x8*)(sPh + (qoff +  0 + l15) * LW + s * 32 + quad * 8);
            bf16x8 aP1 = *(const bf16x8*)(sPh + (qoff + 16 + l15) * LW + s * 32 + quad * 8);
            #pragma unroll
            for (int jd = 0; jd < 4; ++jd) {
                bf16x8 bV = *(const bf16x8*)(sV + (16 * jd + l15) * LW + s * 32 + quad * 8);
                O[0][jd] = __builtin_amdgcn_mfma_f32_16x16x32_bf16(aP0, bV, O[0][jd], 0, 0, 0);
                O[1][jd] = __builtin_amdgcn_mfma_f32_16x16x32_bf16(aP1, bV, O[1][jd], 0, 0, 0);
            }
        }
    }

    // softmax denominators: reduce across the 16 lanes of each quad-group
    float rinv[2][4];
    #pragma unroll
    for (int i = 0; i < 2; ++i)
        #pragma unroll
        for (int r = 0; r < 4; ++r) {
            float s = lacc[i][r];
            s += __shfl_xor(s, 1, 64);
            s += __shfl_xor(s, 2, 64);
            s += __shfl_xor(s, 4, 64);
            s += __shfl_xor(s, 8, 64);
            rinv[i][r] = 1.0f / s;
        }

    __syncthreads();   // all waves done reading sK/sV/sP before overwrite
    // transpose O through LDS: sT[head][dim][query]
    float* sTh = sT + hloc * 64 * 68;
    #pragma unroll
    for (int i = 0; i < 2; ++i)
        #pragma unroll
        for (int jd = 0; jd < 4; ++jd)
            #pragma unroll
            for (int r = 0; r < 4; ++r)
                sTh[(16 * jd + l15) * 68 + qoff + 16 * i + quad * 4 + r] = O[i][jd][r] * rinv[i][r];
    __syncthreads();

    // coalesced writeout: 2 heads x 64 dims x 64 queries
    #pragma unroll
    for (int u = 0; u < 8; ++u) {
        int flat = tid + 256 * u;       // 0..2047 chunks of float4
        int hh   = flat >> 10;
        int rowd = (flat >> 4) & 63;
        int ch   = (flat & 15) * 4;
        f32x4 v = *(const f32x4*)(sT + hh * 64 * 68 + rowd * 68 + ch);
        *(f32x4*)(attn_out + ((size_t)(b * 256 + (blockIdx.y * 2 + hh) * 64 + rowd)) * NN + nb + ch) = v;
    }
}

// ---------------------------------------------------------------------------
// K3: proj[b][c][n] = sum_o pw[c][o] * attn[b][o][n] + pb[c]   (fp32 VALU)
// ---------------------------------------------------------------------------
__global__ __launch_bounds__(256) void proj_gemm_k(
    const float* __restrict__ ain, const float* __restrict__ pw,
    const float* __restrict__ pb, float* __restrict__ pout)
{
    __shared__ float Wl[64][17];
    __shared__ float Xl[16][68];
    const int tid = threadIdx.x;
    const int nb = blockIdx.x * 64;
    const int ob = blockIdx.y * 64;
    const int b  = blockIdx.z;
    const int tn = (tid & 15) * 4;
    const int to = (tid >> 4) * 4;

    const int wrow = tid >> 2;
    const int wc4  = (tid & 3) * 4;
    const float* wsrc = pw + (size_t)(ob + wrow) * CCH;

    const int xrow = tid >> 4;
    const int xn4  = (tid & 15) * 4;
    const float* xsrc = ain + ((size_t)b * CCH + xrow) * NN + nb + xn4;

    float acc[4][4] = {};

    for (int c0 = 0; c0 < CCH; c0 += 16) {
        float4 wv = *(const float4*)(wsrc + c0 + wc4);
        float4 xv = *(const float4*)(xsrc + (size_t)c0 * NN);
        Wl[wrow][wc4+0] = wv.x; Wl[wrow][wc4+1] = wv.y;
        Wl[wrow][wc4+2] = wv.z; Wl[wrow][wc4+3] = wv.w;
        Xl[xrow][xn4+0] = xv.x; Xl[xrow][xn4+1] = xv.y;
        Xl[xrow][xn4+2] = xv.z; Xl[xrow][xn4+3] = xv.w;
        __syncthreads();
        #pragma unroll
        for (int kk = 0; kk < 16; ++kk) {
            float a0 = Wl[to+0][kk], a1 = Wl[to+1][kk];
            float a2 = Wl[to+2][kk], a3 = Wl[to+3][kk];
            float b0 = Xl[kk][tn+0], b1 = Xl[kk][tn+1];
            float b2 = Xl[kk][tn+2], b3 = Xl[kk][tn+3];
            acc[0][0] += a0*b0; acc[0][1] += a0*b1; acc[0][2] += a0*b2; acc[0][3] += a0*b3;
            acc[1][0] += a1*b0; acc[1][1] += a1*b1; acc[1][2] += a1*b2; acc[1][3] += a1*b3;
            acc[2][0] += a2*b0; acc[2][1] += a2*b1; acc[2][2] += a2*b2; acc[2][3] += a2*b3;
            acc[3][0] += a3*b0; acc[3][1] += a3*b1; acc[3][2] += a3*b2; acc[3][3] += a3*b3;
        }
        __syncthreads();
    }
    float* dst = pout + ((size_t)b * CCH + ob + to) * NN + nb + tn;
    #pragma unroll
    for (int i = 0; i < 4; ++i) {
        float bias = pb[ob + to + i];
        float4 v = make_float4(acc[i][0] + bias, acc[i][1] + bias,
                               acc[i][2] + bias, acc[i][3] + bias);
        *(float4*)(dst + (size_t)i * NN) = v;
    }
}

// ---------------------------------------------------------------------------
// K4: per-channel batch stats -> scale/shift
// ---------------------------------------------------------------------------
__global__ __launch_bounds__(256) void bn_stats_k(
    const float* __restrict__ proj, const float* __restrict__ gamma,
    const float* __restrict__ beta, float* __restrict__ stats)
{
    const int c = blockIdx.x;
    const int tid = threadIdx.x;
    float s = 0.f, s2 = 0.f;
    for (int b = 0; b < BB; ++b) {
        const float* p = proj + ((size_t)b * CCH + c) * NN;
        for (int n = tid * 4; n < NN; n += 1024) {
            float4 v = *(const float4*)(p + n);
            s  += v.x + v.y + v.z + v.w;
            s2 += v.x*v.x + v.y*v.y + v.z*v.z + v.w*v.w;
        }
    }
    __shared__ float rs[256], rs2[256];
    rs[tid] = s; rs2[tid] = s2;
    __syncthreads();
    for (int off = 128; off > 0; off >>= 1) {
        if (tid < off) { rs[tid] += rs[tid + off]; rs2[tid] += rs2[tid + off]; }
        __syncthreads();
    }
    if (tid == 0) {
        const float inv_n = 1.0f / (float)(BB * NN);
        float mean = rs[0] * inv_n;
        float var  = rs2[0] * inv_n - mean * mean;
        float sc = gamma[c] * rsqrtf(var + BN_EPS);
        stats[c] = sc;
        stats[CCH + c] = beta[c] - mean * sc;
    }
}

// ---------------------------------------------------------------------------
// K5: out = scale[c]*proj + shift[c] + x
// ---------------------------------------------------------------------------
__global__ __launch_bounds__(256) void bn_apply_k(
    const float* __restrict__ proj, const float* __restrict__ x,
    const float* __restrict__ stats, float* __restrict__ out)
{
    size_t idx = ((size_t)blockIdx.x * 256 + threadIdx.x) * 4;
    const size_t total = (size_t)BB * CCH * NN;
    if (idx >= total) return;
    int c = (int)((idx / NN) % CCH);
    float sc = stats[c], sh = stats[CCH + c];
    float4 p  = *(const float4*)(proj + idx);
    float4 xv = *(const float4*)(x + idx);
    float4 r;
    r.x = sc * p.x + sh + xv.x;
    r.y = sc * p.y + sh + xv.y;
    r.z = sc * p.z + sh + xv.z;
    r.w = sc * p.w + sh + xv.w;
    *(float4*)(out + idx) = r;
}

extern "C" void kernel_launch(void* const* d_in, const int* in_sizes, int n_in,
                              void* d_out, int out_size, void* d_ws, size_t ws_size,
                              hipStream_t stream)
{
    const float* x     = (const float*)d_in[0];
    const float* qw    = (const float*)d_in[1];
    const float* kw    = (const float*)d_in[2];
    const float* vw    = (const float*)d_in[3];
    const float* pw    = (const float*)d_in[4];
    const float* pb    = (const float*)d_in[5];
    const float* gamma = (const float*)d_in[6];
    const float* beta  = (const float*)d_in[7];
    float* out = (float*)d_out;

    char* ws = (char*)d_ws;
    // proj (fp32, 18.9 MB) overlaps Qt/Kt/Vn (bf16, 14.1 MB) — Q/K/V dead by K3.
    unsigned short* Qt = (unsigned short*)ws;                        // 9,437,184 B
    unsigned short* Kt = (unsigned short*)(ws + 9437184);            // 2,359,296 B
    unsigned short* Vn = (unsigned short*)(ws + 11796480);           // 2,359,296 B
    float* proj  = (float*)ws;                                       // 18,874,368 B
    float* attn  = (float*)(ws + 18874368);                          // 18,874,368 B
    float* stats = (float*)(ws + 37748736);                          // 2 KB

    dim3 g1(NN / 64, QKV_ROWS / 64, BB);
    qkv_gemm_k<<<g1, 256, 0, stream>>>(x, qw, kw, vw, Qt, Kt, Vn);

    dim3 g2(NN / 64, NH / 2, BB);
    attn_k<<<g2, 256, 0, stream>>>(Qt, Kt, Vn, attn);

    dim3 g3(NN / 64, CCH / 64, BB);
    proj_gemm_k<<<g3, 256, 0, stream>>>(attn, pw, pb, proj);

    bn_stats_k<<<CCH, 256, 0, stream>>>(proj, gamma, beta, stats);

    int total4 = BB * CCH * NN / 4;
    bn_apply_k<<<(total4 + 255) / 256, 256, 0, stream>>>(proj, x, stats, out);
}